// Round 9
// baseline (183.237 us; speedup 1.0000x reference)
//
#include <hip/hip_runtime.h>

#define N_NODES 100000
#define N_EDGES 1200000
#define N_GRAPHS 2048
#define NBKT 36   // 8 shape + 8 color + 20 pos
#define CAPA 16   // level-1 slab: one 64B line per node
#define CAPB 32   // overflow slab; total 48, P(deg>48|Poisson 12) ~ 1e-13
#define NPART 8   // dst partitions == XCDs
#define NCHUNK 256

typedef unsigned int uint;
typedef unsigned short ushort;
typedef __attribute__((ext_vector_type(8))) short short8;  // bf16x8 MFMA operand
typedef __attribute__((ext_vector_type(4))) float f32x4;   // 16x16 accumulator
typedef __attribute__((ext_vector_type(4))) int i32x4;     // for nontemporal loads

__device__ __forceinline__ int atomAddI(int* p, int v) {
    return __hip_atomic_fetch_add(p, v, __ATOMIC_RELAXED, __HIP_MEMORY_SCOPE_AGENT);
}
__device__ __forceinline__ int clampPos(int v) { return min(max(v, 0), 19); }
__device__ __forceinline__ uint f2bf(float f) {            // RNE f32->bf16 bits
    uint b = __float_as_uint(f);
    return (b + 0x7fffu + ((b >> 16) & 1u)) >> 16;
}

// Fused init: fold embeddings into W1 tables, zero cursor, pack x, and build
// bf16 transposed stacked weight WstkT[col][k] (k<64 -> W2r[k], else W2l[k-64]).
__global__ __launch_bounds__(256) void k_init(
    const int* __restrict__ x,
    const float* __restrict__ se, const float* __restrict__ ce,
    const float* __restrict__ pe,
    const float* __restrict__ W1l, const float* __restrict__ W1r,
    const float* __restrict__ W2l, const float* __restrict__ W2r,
    float* __restrict__ W1eff, float* __restrict__ Rtab,
    ushort* __restrict__ WstkT,
    int* __restrict__ cursor, int* __restrict__ xpk) {
    int t = blockIdx.x * 256 + threadIdx.x;
    if (t < NBKT * 64) {
        int bkt = t / 64, j = t % 64;
        const float* erow; int f0;
        if (bkt < 8)       { erow = se + bkt * 16;        f0 = 0;  }
        else if (bkt < 16) { erow = ce + (bkt - 8) * 16;  f0 = 16; }
        else               { erow = pe + (bkt - 16) * 16; f0 = 32; }
        float al = 0.f, ar = 0.f;
        #pragma unroll
        for (int f = 0; f < 16; ++f) {
            al = fmaf(erow[f], W1l[(f0 + f) * 64 + j], al);
            ar = fmaf(erow[f], W1r[(f0 + f) * 64 + j], ar);
        }
        W1eff[t] = al; Rtab[t] = ar;
    }
    if (t < 64 * 128) {
        int col = t >> 7, k = t & 127;
        float wv = (k < 64) ? W2r[k * 64 + col] : W2l[(k - 64) * 64 + col];
        WstkT[col * 128 + k] = (ushort)f2bf(wv);
    }
    for (int i = t; i < N_NODES; i += 256 * 256) {
        cursor[i] = 0;
        int xs = x[i * 3 + 0], xc = x[i * 3 + 1], xp = clampPos(x[i * 3 + 2]);
        xpk[i] = xs | (xc << 8) | (xp << 16);
    }
}

// Bucketed CSR build, XCD-partitioned by dst range. Edge stream is read with
// NON-TEMPORAL loads so it doesn't evict the partition's slab/cursor working
// set (2.45 MB) from the XCD's 4 MB L2 -> slab lines stay resident across all
// ~12 re-dirties and write back once at the end.
__global__ __launch_bounds__(256) void k_fill(const int* __restrict__ ei,
                                              int* __restrict__ cursor,
                                              int* __restrict__ slabA,
                                              int* __restrict__ slabB) {
    int part = blockIdx.x & (NPART - 1);
    int chunk = blockIdx.x >> 3;
    int d_lo = part * (N_NODES / NPART);
    int d_hi = d_lo + (N_NODES / NPART);
    const int per = 4688;                        // 256*4688 >= N_EDGES, %4==0
    int base = chunk * per;
    int e1 = min(base + per, N_EDGES);
    for (int e = base + (threadIdx.x << 2); e < e1; e += 1024) {
        i32x4 d4 = __builtin_nontemporal_load((const i32x4*)(ei + N_EDGES + e));
        i32x4 s4 = __builtin_nontemporal_load((const i32x4*)(ei + e));
        #pragma unroll
        for (int i = 0; i < 4; ++i) {
            int d = d4[i];
            if (d >= d_lo && d < d_hi) {
                int pos = atomAddI(&cursor[d], 1);
                if (pos < CAPA) slabA[d * CAPA + pos] = s4[i];
                else if (pos < CAPA + CAPB) slabB[d * CAPB + pos - CAPA] = s4[i];
            }
        }
    }
}

__device__ __forceinline__ int slabAt(const int* __restrict__ slabA,
                                      const int* __restrict__ slabB,
                                      int row, int idx) {
    return (idx < CAPA) ? slabA[row * CAPA + idx] : slabB[row * CAPB + idx - CAPA];
}

// h1 = relu( mean_agg + self + b1 ); agg via 36-bucket ballot histogram.
// Writes ONLY packed bf16 into Ab[row][0:64) (self half of the K=128 matrix).
__global__ __launch_bounds__(256) void k_layer1(
    const int* __restrict__ xpk, const int* __restrict__ cursor,
    const int* __restrict__ slabA, const int* __restrict__ slabB,
    const float* __restrict__ W1eff, const float* __restrict__ Rtab,
    const float* __restrict__ b1, uint* __restrict__ AbU) {
    __shared__ float sW[NBKT * 64];
    __shared__ float sR[NBKT * 64];
    __shared__ float sb[64];
    __shared__ int   sx[16];
    for (int i = threadIdx.x; i < NBKT * 64; i += 256) { sW[i] = W1eff[i]; sR[i] = Rtab[i]; }
    if (threadIdx.x < 64) sb[threadIdx.x] = b1[threadIdx.x];
    int row0 = blockIdx.x * 16;
    if (threadIdx.x < 16) sx[threadIdx.x] = xpk[row0 + threadIdx.x];
    __syncthreads();
    int wave = threadIdx.x >> 6, j = threadIdx.x & 63;
    for (int rr = 0; rr < 4; ++rr) {
        int r = wave * 4 + rr;
        int row = row0 + r;
        int deg = cursor[row];
        int m = min(deg, CAPA + CAPB);
        int xs = -1, xc = -1, xp = -1;
        if (j < m) {
            int p = xpk[slabAt(slabA, slabB, row, j)];
            xs = p & 0xff; xc = (p >> 8) & 0xff; xp = p >> 16;
        }
        float acc = 0.f;
        #pragma unroll
        for (int b = 0; b < 8; ++b) {
            float cs = (float)__popcll(__ballot(xs == b));
            float cc = (float)__popcll(__ballot(xc == b));
            acc = fmaf(cs, sW[b * 64 + j], acc);
            acc = fmaf(cc, sW[(8 + b) * 64 + j], acc);
        }
        #pragma unroll
        for (int b = 0; b < 20; ++b) {
            float cp = (float)__popcll(__ballot(xp == b));
            acc = fmaf(cp, sW[(16 + b) * 64 + j], acc);
        }
        int p0 = sx[r];
        int xs0 = p0 & 0xff, xc0 = (p0 >> 8) & 0xff, xp0 = p0 >> 16;
        float self = sR[xs0 * 64 + j] + sR[(8 + xc0) * 64 + j] + sR[(16 + xp0) * 64 + j];
        float v = fmaxf(acc / fmaxf((float)deg, 1.0f) + self + sb[j], 0.0f);
        uint rb = f2bf(v);
        uint nxt = __shfl_down(rb, 1);
        if ((j & 1) == 0) AbU[(size_t)row * 64 + (j >> 1)] = rb | (nxt << 16);
    }
}

// Layer-2 neighbor mean from bf16 self-half of Ab; writes bf16 agg-half.
// One wave = 2 rows (32 lanes each, lane l = features 2l,2l+1), no LDS.
__global__ __launch_bounds__(256) void k_gather(
    uint* __restrict__ AbU, const int* __restrict__ cursor,
    const int* __restrict__ slabA, const int* __restrict__ slabB) {
    int gid = blockIdx.x * 256 + threadIdx.x;
    int wid = gid >> 6;
    int lane = threadIdx.x & 63;
    int half = lane >> 5, l = lane & 31;
    int row = wid * 2 + half;
    if (row >= N_NODES) return;
    int deg = cursor[row];
    int m = min(deg, CAPA + CAPB);
    int nb0 = (l < m)      ? slabAt(slabA, slabB, row, l)      : 0;
    int nb1 = (l + 32 < m) ? slabB[row * CAPB + l + 32 - CAPA] : 0;
    float ax = 0.f, ay = 0.f;
    int d = 0;
    for (; d + 2 <= m; d += 2) {
        int s0 = __shfl((d < 32) ? nb0 : nb1, (half << 5) | (d & 31));
        int s1 = __shfl((d + 1 < 32) ? nb0 : nb1, (half << 5) | ((d + 1) & 31));
        uint v0 = AbU[(size_t)s0 * 64 + l];
        uint v1 = AbU[(size_t)s1 * 64 + l];
        ax += __uint_as_float(v0 << 16) + __uint_as_float(v1 << 16);
        ay += __uint_as_float(v0 & 0xffff0000u) + __uint_as_float(v1 & 0xffff0000u);
    }
    if (d < m) {
        int s = __shfl((d < 32) ? nb0 : nb1, (half << 5) | (d & 31));
        uint v = AbU[(size_t)s * 64 + l];
        ax += __uint_as_float(v << 16);
        ay += __uint_as_float(v & 0xffff0000u);
    }
    float inv = 1.0f / fmaxf((float)deg, 1.0f);
    AbU[(size_t)row * 64 + 32 + l] = f2bf(ax * inv) | (f2bf(ay * inv) << 16);
}

// h2 = relu( [h1|agg](bf16, K=128) @ [W2r;W2l] + b2 ) via MFMA 16x16x32 bf16.
// Weights from precomputed bf16 WstkT (one short8 load per fragment); A loaded
// direct from global (block-local 16KB window, L2-hot); zero LDS.
// Fragment k-labeling (both A and B): k = kb*32 + (lane>>4)*8 + e.
__global__ __launch_bounds__(256) void k_gemm(
    const uint* __restrict__ AbU, const ushort* __restrict__ WstkT,
    const float* __restrict__ b2, float* __restrict__ h2) {
    int w = threadIdx.x >> 6, lane = threadIdx.x & 63;
    int lo16 = lane & 15, hi4 = lane >> 4;
    short8 bfr[4][4];
    #pragma unroll
    for (int nb = 0; nb < 4; ++nb) {
        #pragma unroll
        for (int kb = 0; kb < 4; ++kb)
            bfr[nb][kb] = *(const short8*)(WstkT + (nb * 16 + lo16) * 128 + kb * 32 + hi4 * 8);
    }
    float bb[4];
    #pragma unroll
    for (int nb = 0; nb < 4; ++nb) bb[nb] = b2[nb * 16 + lo16];

    int row0 = blockIdx.x * 64 + w * 16;
    int arow = min(row0 + lo16, N_NODES - 1);
    const short8* Arow = (const short8*)(AbU + (size_t)arow * 64);
    short8 a8[4];
    #pragma unroll
    for (int kb = 0; kb < 4; ++kb) a8[kb] = Arow[kb * 4 + hi4];   // k = kb*32 + hi4*8 + e

    f32x4 acc[4] = {{0,0,0,0},{0,0,0,0},{0,0,0,0},{0,0,0,0}};
    #pragma unroll
    for (int kb = 0; kb < 4; ++kb) {
        #pragma unroll
        for (int nb = 0; nb < 4; ++nb)
            acc[nb] = __builtin_amdgcn_mfma_f32_16x16x32_bf16(a8[kb], bfr[nb][kb], acc[nb], 0, 0, 0);
    }
    // C layout (m89-verified): col = lane&15, row = (lane>>4)*4 + reg
    #pragma unroll
    for (int nb = 0; nb < 4; ++nb) {
        #pragma unroll
        for (int r = 0; r < 4; ++r) {
            int orow = row0 + hi4 * 4 + r;
            if (orow < N_NODES)
                h2[(size_t)orow * 64 + nb * 16 + lo16] = fmaxf(acc[nb][r] + bb[nb], 0.f);
        }
    }
}

__device__ __forceinline__ int lowerBound(const int* __restrict__ b, int n, int v) {
    int lo = 0, hi = n;
    while (lo < hi) { int mid = (lo + hi) >> 1; if (b[mid] < v) lo = mid + 1; else hi = mid; }
    return lo;
}

// Fused graph mean-pool + classifier; 4 independent partial sums to break the
// serial load chain (only ~2 blocks/CU occupancy here).
__global__ __launch_bounds__(256) void k_pool_final(
    const float* __restrict__ h2, const int* __restrict__ batch,
    const float* __restrict__ Wc, const float* __restrict__ bc,
    float* __restrict__ out) {
    int g = blockIdx.x * 4 + (threadIdx.x >> 6);
    if (g >= N_GRAPHS) return;
    int j = threadIdx.x & 63;
    int lo = lowerBound(batch, N_NODES, g);
    int hi = lowerBound(batch, N_NODES, g + 1);
    float a0 = 0.f, a1 = 0.f, a2 = 0.f, a3 = 0.f;
    int n = lo;
    for (; n + 4 <= hi; n += 4) {
        a0 += h2[(size_t)n * 64 + j];
        a1 += h2[(size_t)(n + 1) * 64 + j];
        a2 += h2[(size_t)(n + 2) * 64 + j];
        a3 += h2[(size_t)(n + 3) * 64 + j];
    }
    for (; n < hi; ++n) a0 += h2[(size_t)n * 64 + j];
    float mean = ((a0 + a1) + (a2 + a3)) / fmaxf((float)(hi - lo), 1.0f);
    #pragma unroll
    for (int c = 0; c < 10; ++c) {
        float p = mean * Wc[j * 10 + c];
        #pragma unroll
        for (int off = 32; off >= 1; off >>= 1) p += __shfl_down(p, off);
        if (j == 0) out[g * 10 + c] = p + bc[c];
    }
}

extern "C" void kernel_launch(void* const* d_in, const int* in_sizes, int n_in,
                              void* d_out, int out_size, void* d_ws, size_t ws_size,
                              hipStream_t stream) {
    const int* x     = (const int*)d_in[0];
    const int* ei    = (const int*)d_in[1];
    const int* batch = (const int*)d_in[2];
    const float* se  = (const float*)d_in[4];
    const float* ce  = (const float*)d_in[5];
    const float* pe  = (const float*)d_in[6];
    const float* W1l = (const float*)d_in[7];
    const float* W1r = (const float*)d_in[8];
    const float* b1  = (const float*)d_in[9];
    const float* W2l = (const float*)d_in[10];
    const float* W2r = (const float*)d_in[11];
    const float* b2  = (const float*)d_in[12];
    const float* Wc  = (const float*)d_in[13];
    const float* bc  = (const float*)d_in[14];

    float* ws    = (float*)d_ws;
    uint*  AbU   = (uint*)ws;                   // [0, 6.4M) packed bf16 [N][64]
    float* h2    = ws + 6400000;                // [6.4M, 12.8M)
    int*   slabA = (int*)(ws + 12800000);       // 1.6M ints (100k x 16, 64B/row)
    int*   slabB = (int*)(ws + 14400000);       // 3.2M ints (100k x 32 overflow)
    int*   cursor= (int*)(ws + 17600000);       // 100k
    int*   xpk   = (int*)(ws + 17700000);       // 100k
    float* W1eff = ws + 17800000;               // 2304
    float* Rtab  = ws + 17803000;               // 2304
    ushort* WstkT= (ushort*)(ws + 17806000);    // 8192 ushorts (16B-aligned)

    k_init<<<256, 256, 0, stream>>>(x, se, ce, pe, W1l, W1r, W2l, W2r,
                                    W1eff, Rtab, WstkT, cursor, xpk);
    k_fill<<<NPART * NCHUNK, 256, 0, stream>>>(ei, cursor, slabA, slabB);
    k_layer1<<<N_NODES / 16, 256, 0, stream>>>(xpk, cursor, slabA, slabB, W1eff, Rtab, b1, AbU);
    k_gather<<<12500, 256, 0, stream>>>(AbU, cursor, slabA, slabB);
    k_gemm<<<(N_NODES + 63) / 64, 256, 0, stream>>>(AbU, WstkT, b2, h2);
    k_pool_final<<<(N_GRAPHS + 3) / 4, 256, 0, stream>>>(h2, batch, Wc, bc, (float*)d_out);
}

// Round 10
// 147.497 us; speedup vs baseline: 1.2423x; 1.2423x over previous
//
#include <hip/hip_runtime.h>

#define N_NODES 100000
#define N_EDGES 1200000
#define N_GRAPHS 2048
#define NBKT 36    // 8 shape + 8 color + 20 pos
#define CAPA 16    // slabA slots per node (one 64B line)
#define CAPB 32    // slabB overflow; total 48, P(deg>48|Poisson 12) ~ 1e-13
#define NBUCK 500  // dst buckets for binning
#define DPB 200    // dsts per bucket (500*200 = 100000 exactly)
#define BCAP 4864  // per-bucket edge capacity (mean 2400, +50 sigma)
#define TILE 4096  // edges per k_bin block

typedef unsigned int uint;
typedef unsigned short ushort;
typedef __attribute__((ext_vector_type(8))) short short8;  // bf16x8 MFMA operand
typedef __attribute__((ext_vector_type(4))) float f32x4;   // 16x16 accumulator

__device__ __forceinline__ int atomAddI(int* p, int v) {
    return __hip_atomic_fetch_add(p, v, __ATOMIC_RELAXED, __HIP_MEMORY_SCOPE_AGENT);
}
__device__ __forceinline__ int clampPos(int v) { return min(max(v, 0), 19); }
__device__ __forceinline__ uint f2bf(float f) {            // RNE f32->bf16 bits
    uint b = __float_as_uint(f);
    return (b + 0x7fffu + ((b >> 16) & 1u)) >> 16;
}
// d/200 for d<100000, exact: d/200 = (d>>3)/25; x*5243>>17 == x/25 for x<=12500
__device__ __forceinline__ int bucketOf(int d) {
    return (int)(((uint)((d >> 3) * 5243)) >> 17);
}

// Fused init: fold embeddings into W1 tables, zero bucket cursors, pack x,
// build bf16 stacked-transposed weight WstkT[col][k] (k<64->W2r, else W2l).
__global__ __launch_bounds__(256) void k_init(
    const int* __restrict__ x,
    const float* __restrict__ se, const float* __restrict__ ce,
    const float* __restrict__ pe,
    const float* __restrict__ W1l, const float* __restrict__ W1r,
    const float* __restrict__ W2l, const float* __restrict__ W2r,
    float* __restrict__ W1eff, float* __restrict__ Rtab,
    ushort* __restrict__ WstkT,
    int* __restrict__ gcur, int* __restrict__ xpk) {
    int t = blockIdx.x * 256 + threadIdx.x;
    if (t < NBKT * 64) {
        int bkt = t / 64, j = t % 64;
        const float* erow; int f0;
        if (bkt < 8)       { erow = se + bkt * 16;        f0 = 0;  }
        else if (bkt < 16) { erow = ce + (bkt - 8) * 16;  f0 = 16; }
        else               { erow = pe + (bkt - 16) * 16; f0 = 32; }
        float al = 0.f, ar = 0.f;
        #pragma unroll
        for (int f = 0; f < 16; ++f) {
            al = fmaf(erow[f], W1l[(f0 + f) * 64 + j], al);
            ar = fmaf(erow[f], W1r[(f0 + f) * 64 + j], ar);
        }
        W1eff[t] = al; Rtab[t] = ar;
    }
    if (t < 64 * 128) {
        int col = t >> 7, k = t & 127;
        float wv = (k < 64) ? W2r[k * 64 + col] : W2l[(k - 64) * 64 + col];
        WstkT[col * 128 + k] = (ushort)f2bf(wv);
    }
    if (t < NBUCK) gcur[t] = 0;
    for (int i = t; i < N_NODES; i += 256 * 256) {
        int xs = x[i * 3 + 0], xc = x[i * 3 + 1], xp = clampPos(x[i * 3 + 2]);
        xpk[i] = xs | (xc << 8) | (xp << 16);
    }
}

// Phase 1: bin edges by dst-bucket. LDS histogram + wave scan + LDS reorder,
// then bulk copy each bucket run to the fixed-stride binned buffer.
// Global atomics: NBUCK per block (~147K total) instead of 1/edge.
__global__ __launch_bounds__(256) void k_bin(const int* __restrict__ ei,
                                             int* __restrict__ gcur,
                                             int2* __restrict__ binned) {
    __shared__ int hist[NBUCK], offs[NBUCK], runc[NBUCK], gbase[NBUCK];
    __shared__ int2 stag[TILE];
    int tid = threadIdx.x;
    int tile_base = blockIdx.x * TILE;
    int tile_n = min(TILE, N_EDGES - tile_base);
    int n4 = tile_n >> 2;                       // N_EDGES%4==0 -> tile_n%4==0
    const int4* s4p = (const int4*)(ei + tile_base);
    const int4* d4p = (const int4*)(ei + N_EDGES + tile_base);

    for (int t = tid; t < NBUCK; t += 256) hist[t] = 0;
    __syncthreads();
    for (int k = tid; k < n4; k += 256) {
        int4 d4 = d4p[k];
        #pragma unroll
        for (int i = 0; i < 4; ++i) atomicAdd(&hist[bucketOf((&d4.x)[i])], 1);
    }
    __syncthreads();
    if (tid < 64) {                              // exclusive scan, wave 0
        int carry = 0;
        for (int c = 0; c < 8; ++c) {
            int idx = c * 64 + tid;
            int v = (idx < NBUCK) ? hist[idx] : 0;
            int orig = v;
            #pragma unroll
            for (int o = 1; o < 64; o <<= 1) {
                int u = __shfl_up(v, o);
                if (tid >= o) v += u;
            }
            if (idx < NBUCK) offs[idx] = carry + v - orig;
            carry += __shfl(v, 63);
        }
    }
    __syncthreads();
    for (int t = tid; t < NBUCK; t += 256) runc[t] = offs[t];
    __syncthreads();
    for (int k = tid; k < n4; k += 256) {        // reorder into LDS staging
        int4 d4 = d4p[k];
        int4 s4 = s4p[k];
        #pragma unroll
        for (int i = 0; i < 4; ++i) {
            int b = bucketOf((&d4.x)[i]);
            int pos = atomicAdd(&runc[b], 1);
            stag[pos] = make_int2((&s4.x)[i], (&d4.x)[i]);
        }
    }
    __syncthreads();
    for (int t = tid; t < NBUCK; t += 256) gbase[t] = atomAddI(&gcur[t], hist[t]);
    __syncthreads();
    for (int i = tid; i < tile_n; i += 256) {    // bulk copy runs to global
        int2 p = stag[i];
        int b = bucketOf(p.y);
        int o = gbase[b] + (i - offs[b]);
        if (o < BCAP) binned[(size_t)b * BCAP + o] = p;
    }
}

// Phase 2: one block per bucket; build 200 slab rows ENTIRELY in LDS (all
// slot atomics in LDS), then fully-coalesced copy-out. No global atomics,
// no scattered global stores. Unused LDS slots hold garbage - never read
// (deg-guarded downstream).
__global__ __launch_bounds__(256) void k_place(const int2* __restrict__ binned,
                                               const int* __restrict__ gcur,
                                               int* __restrict__ cursor,
                                               int* __restrict__ slabA,
                                               int* __restrict__ slabB) {
    __shared__ int lslab[DPB][CAPA + CAPB];
    __shared__ int lcur[DPB];
    int b = blockIdx.x;
    int tid = threadIdx.x;
    if (tid < DPB) lcur[tid] = 0;
    __syncthreads();
    int n = min(gcur[b], BCAP);
    const int2* in = binned + (size_t)b * BCAP;
    for (int i = tid; i < n; i += 256) {
        int2 p = in[i];
        int local = p.y - b * DPB;
        int slot = atomicAdd(&lcur[local], 1);
        if (slot < CAPA + CAPB) lslab[local][slot] = p.x;
    }
    __syncthreads();
    for (int i = tid; i < DPB * CAPA; i += 256)
        slabA[b * DPB * CAPA + i] = lslab[i >> 4][i & 15];
    for (int i = tid; i < DPB * CAPB; i += 256)
        slabB[b * DPB * CAPB + i] = lslab[i >> 5][CAPA + (i & 31)];
    if (tid < DPB) cursor[b * DPB + tid] = lcur[tid];
}

__device__ __forceinline__ int slabAt(const int* __restrict__ slabA,
                                      const int* __restrict__ slabB,
                                      int row, int idx) {
    return (idx < CAPA) ? slabA[row * CAPA + idx] : slabB[row * CAPB + idx - CAPA];
}

// h1 = relu( mean_agg + self + b1 ); agg via 36-bucket ballot histogram.
// Writes packed bf16 into Ab[row][0:64) (self half of the K=128 matrix).
__global__ __launch_bounds__(256) void k_layer1(
    const int* __restrict__ xpk, const int* __restrict__ cursor,
    const int* __restrict__ slabA, const int* __restrict__ slabB,
    const float* __restrict__ W1eff, const float* __restrict__ Rtab,
    const float* __restrict__ b1, uint* __restrict__ AbU) {
    __shared__ float sW[NBKT * 64];
    __shared__ float sR[NBKT * 64];
    __shared__ float sb[64];
    __shared__ int   sx[16];
    for (int i = threadIdx.x; i < NBKT * 64; i += 256) { sW[i] = W1eff[i]; sR[i] = Rtab[i]; }
    if (threadIdx.x < 64) sb[threadIdx.x] = b1[threadIdx.x];
    int row0 = blockIdx.x * 16;
    if (threadIdx.x < 16) sx[threadIdx.x] = xpk[row0 + threadIdx.x];
    __syncthreads();
    int wave = threadIdx.x >> 6, j = threadIdx.x & 63;
    for (int rr = 0; rr < 4; ++rr) {
        int r = wave * 4 + rr;
        int row = row0 + r;
        int deg = cursor[row];
        int m = min(deg, CAPA + CAPB);
        int xs = -1, xc = -1, xp = -1;
        if (j < m) {
            int p = xpk[slabAt(slabA, slabB, row, j)];
            xs = p & 0xff; xc = (p >> 8) & 0xff; xp = p >> 16;
        }
        float acc = 0.f;
        #pragma unroll
        for (int b = 0; b < 8; ++b) {
            float cs = (float)__popcll(__ballot(xs == b));
            float cc = (float)__popcll(__ballot(xc == b));
            acc = fmaf(cs, sW[b * 64 + j], acc);
            acc = fmaf(cc, sW[(8 + b) * 64 + j], acc);
        }
        #pragma unroll
        for (int b = 0; b < 20; ++b) {
            float cp = (float)__popcll(__ballot(xp == b));
            acc = fmaf(cp, sW[(16 + b) * 64 + j], acc);
        }
        int p0 = sx[r];
        int xs0 = p0 & 0xff, xc0 = (p0 >> 8) & 0xff, xp0 = p0 >> 16;
        float self = sR[xs0 * 64 + j] + sR[(8 + xc0) * 64 + j] + sR[(16 + xp0) * 64 + j];
        float v = fmaxf(acc / fmaxf((float)deg, 1.0f) + self + sb[j], 0.0f);
        uint rb = f2bf(v);
        uint nxt = __shfl_down(rb, 1);
        if ((j & 1) == 0) AbU[(size_t)row * 64 + (j >> 1)] = rb | (nxt << 16);
    }
}

// Layer-2 neighbor mean from bf16 self-half of Ab; writes bf16 agg-half.
// One wave = 2 rows (32 lanes each, lane l = features 2l,2l+1), no LDS.
__global__ __launch_bounds__(256) void k_gather(
    uint* __restrict__ AbU, const int* __restrict__ cursor,
    const int* __restrict__ slabA, const int* __restrict__ slabB) {
    int gid = blockIdx.x * 256 + threadIdx.x;
    int wid = gid >> 6;
    int lane = threadIdx.x & 63;
    int half = lane >> 5, l = lane & 31;
    int row = wid * 2 + half;
    if (row >= N_NODES) return;
    int deg = cursor[row];
    int m = min(deg, CAPA + CAPB);
    int nb0 = (l < m)      ? slabAt(slabA, slabB, row, l)      : 0;
    int nb1 = (l + 32 < m) ? slabB[row * CAPB + l + 32 - CAPA] : 0;
    float ax = 0.f, ay = 0.f;
    int d = 0;
    for (; d + 2 <= m; d += 2) {
        int s0 = __shfl((d < 32) ? nb0 : nb1, (half << 5) | (d & 31));
        int s1 = __shfl((d + 1 < 32) ? nb0 : nb1, (half << 5) | ((d + 1) & 31));
        uint v0 = AbU[(size_t)s0 * 64 + l];
        uint v1 = AbU[(size_t)s1 * 64 + l];
        ax += __uint_as_float(v0 << 16) + __uint_as_float(v1 << 16);
        ay += __uint_as_float(v0 & 0xffff0000u) + __uint_as_float(v1 & 0xffff0000u);
    }
    if (d < m) {
        int s = __shfl((d < 32) ? nb0 : nb1, (half << 5) | (d & 31));
        uint v = AbU[(size_t)s * 64 + l];
        ax += __uint_as_float(v << 16);
        ay += __uint_as_float(v & 0xffff0000u);
    }
    float inv = 1.0f / fmaxf((float)deg, 1.0f);
    AbU[(size_t)row * 64 + 32 + l] = f2bf(ax * inv) | (f2bf(ay * inv) << 16);
}

// h2 = relu( [h1|agg](bf16, K=128) @ [W2r;W2l] + b2 ) via MFMA 16x16x32 bf16.
// Fragment k-labeling (both A and B): k = kb*32 + (lane>>4)*8 + e.
__global__ __launch_bounds__(256) void k_gemm(
    const uint* __restrict__ AbU, const ushort* __restrict__ WstkT,
    const float* __restrict__ b2, float* __restrict__ h2) {
    int w = threadIdx.x >> 6, lane = threadIdx.x & 63;
    int lo16 = lane & 15, hi4 = lane >> 4;
    short8 bfr[4][4];
    #pragma unroll
    for (int nb = 0; nb < 4; ++nb) {
        #pragma unroll
        for (int kb = 0; kb < 4; ++kb)
            bfr[nb][kb] = *(const short8*)(WstkT + (nb * 16 + lo16) * 128 + kb * 32 + hi4 * 8);
    }
    float bb[4];
    #pragma unroll
    for (int nb = 0; nb < 4; ++nb) bb[nb] = b2[nb * 16 + lo16];

    int row0 = blockIdx.x * 64 + w * 16;
    int arow = min(row0 + lo16, N_NODES - 1);
    const short8* Arow = (const short8*)(AbU + (size_t)arow * 64);
    short8 a8[4];
    #pragma unroll
    for (int kb = 0; kb < 4; ++kb) a8[kb] = Arow[kb * 4 + hi4];   // k = kb*32+hi4*8+e

    f32x4 acc[4] = {{0,0,0,0},{0,0,0,0},{0,0,0,0},{0,0,0,0}};
    #pragma unroll
    for (int kb = 0; kb < 4; ++kb) {
        #pragma unroll
        for (int nb = 0; nb < 4; ++nb)
            acc[nb] = __builtin_amdgcn_mfma_f32_16x16x32_bf16(a8[kb], bfr[nb][kb], acc[nb], 0, 0, 0);
    }
    // C layout (m89-verified): col = lane&15, row = (lane>>4)*4 + reg
    #pragma unroll
    for (int nb = 0; nb < 4; ++nb) {
        #pragma unroll
        for (int r = 0; r < 4; ++r) {
            int orow = row0 + hi4 * 4 + r;
            if (orow < N_NODES)
                h2[(size_t)orow * 64 + nb * 16 + lo16] = fmaxf(acc[nb][r] + bb[nb], 0.f);
        }
    }
}

__device__ __forceinline__ int lowerBound(const int* __restrict__ b, int n, int v) {
    int lo = 0, hi = n;
    while (lo < hi) { int mid = (lo + hi) >> 1; if (b[mid] < v) lo = mid + 1; else hi = mid; }
    return lo;
}

// Fused graph mean-pool + classifier; 4 independent partial sums.
__global__ __launch_bounds__(256) void k_pool_final(
    const float* __restrict__ h2, const int* __restrict__ batch,
    const float* __restrict__ Wc, const float* __restrict__ bc,
    float* __restrict__ out) {
    int g = blockIdx.x * 4 + (threadIdx.x >> 6);
    if (g >= N_GRAPHS) return;
    int j = threadIdx.x & 63;
    int lo = lowerBound(batch, N_NODES, g);
    int hi = lowerBound(batch, N_NODES, g + 1);
    float a0 = 0.f, a1 = 0.f, a2 = 0.f, a3 = 0.f;
    int n = lo;
    for (; n + 4 <= hi; n += 4) {
        a0 += h2[(size_t)n * 64 + j];
        a1 += h2[(size_t)(n + 1) * 64 + j];
        a2 += h2[(size_t)(n + 2) * 64 + j];
        a3 += h2[(size_t)(n + 3) * 64 + j];
    }
    for (; n < hi; ++n) a0 += h2[(size_t)n * 64 + j];
    float mean = ((a0 + a1) + (a2 + a3)) / fmaxf((float)(hi - lo), 1.0f);
    #pragma unroll
    for (int c = 0; c < 10; ++c) {
        float p = mean * Wc[j * 10 + c];
        #pragma unroll
        for (int off = 32; off >= 1; off >>= 1) p += __shfl_down(p, off);
        if (j == 0) out[g * 10 + c] = p + bc[c];
    }
}

extern "C" void kernel_launch(void* const* d_in, const int* in_sizes, int n_in,
                              void* d_out, int out_size, void* d_ws, size_t ws_size,
                              hipStream_t stream) {
    const int* x     = (const int*)d_in[0];
    const int* ei    = (const int*)d_in[1];
    const int* batch = (const int*)d_in[2];
    const float* se  = (const float*)d_in[4];
    const float* ce  = (const float*)d_in[5];
    const float* pe  = (const float*)d_in[6];
    const float* W1l = (const float*)d_in[7];
    const float* W1r = (const float*)d_in[8];
    const float* b1  = (const float*)d_in[9];
    const float* W2l = (const float*)d_in[10];
    const float* W2r = (const float*)d_in[11];
    const float* b2  = (const float*)d_in[12];
    const float* Wc  = (const float*)d_in[13];
    const float* bc  = (const float*)d_in[14];

    float* ws    = (float*)d_ws;
    uint*  AbU   = (uint*)ws;                   // [0, 6.4M) packed bf16 [N][64]
    float* h2    = ws + 6400000;                // [6.4M, 12.8M)
    int2*  binned= (int2*)ws;                   // [0, 9.728M as ints) ALIASES AbU+h2:
                                                // dead before layer1/gemm write them
    int*   slabA = (int*)(ws + 12800000);       // 1.6M ints (100k x 16)
    int*   slabB = (int*)(ws + 14400000);       // 3.2M ints (100k x 32)
    int*   cursor= (int*)(ws + 17600000);       // 100k
    int*   xpk   = (int*)(ws + 17700000);       // 100k
    float* W1eff = ws + 17800000;               // 2304
    float* Rtab  = ws + 17803000;               // 2304
    ushort* WstkT= (ushort*)(ws + 17806000);    // 8192 ushorts
    int*   gcur  = (int*)(ws + 17812000);       // 500 bucket cursors

    k_init<<<256, 256, 0, stream>>>(x, se, ce, pe, W1l, W1r, W2l, W2r,
                                    W1eff, Rtab, WstkT, gcur, xpk);
    k_bin<<<(N_EDGES + TILE - 1) / TILE, 256, 0, stream>>>(ei, gcur, binned);
    k_place<<<NBUCK, 256, 0, stream>>>(binned, gcur, cursor, slabA, slabB);
    k_layer1<<<N_NODES / 16, 256, 0, stream>>>(xpk, cursor, slabA, slabB, W1eff, Rtab, b1, AbU);
    k_gather<<<12500, 256, 0, stream>>>(AbU, cursor, slabA, slabB);
    k_gemm<<<(N_NODES + 63) / 64, 256, 0, stream>>>(AbU, WstkT, b2, h2);
    k_pool_final<<<(N_GRAPHS + 3) / 4, 256, 0, stream>>>(h2, batch, Wc, bc, (float*)d_out);
}

// Round 11
// 128.864 us; speedup vs baseline: 1.4219x; 1.1446x over previous
//
#include <hip/hip_runtime.h>

#define N_NODES 100000
#define N_EDGES 1200000
#define N_GRAPHS 2048
#define CAPA 16    // slabA slots per node (one 64B line)
#define CAPB 32    // slabB overflow; total 48, P(deg>48|Poisson 12) ~ 1e-13
#define NBUCK 500  // dst buckets for binning
#define DPB 200    // dsts per bucket (500*200 = 100000 exactly)
#define BCAP 4864  // per-bucket edge capacity (mean 2400, +50 sigma)
#define TILE 4096  // edges per k_bin block

typedef unsigned int uint;
typedef unsigned short ushort;
typedef __attribute__((ext_vector_type(8))) short short8;  // bf16x8 MFMA operand
typedef __attribute__((ext_vector_type(4))) float f32x4;   // 16x16 accumulator

__device__ __forceinline__ int atomAddI(int* p, int v) {
    return __hip_atomic_fetch_add(p, v, __ATOMIC_RELAXED, __HIP_MEMORY_SCOPE_AGENT);
}
__device__ __forceinline__ int clampPos(int v) { return min(max(v, 0), 19); }
__device__ __forceinline__ uint f2bf(float f) {            // RNE f32->bf16 bits
    uint b = __float_as_uint(f);
    return (b + 0x7fffu + ((b >> 16) & 1u)) >> 16;
}
// d/200 for d<100000, exact: d/200 = (d>>3)/25; x*5243>>17 == x/25 for x<=12500
__device__ __forceinline__ int bucketOf(int d) {
    return (int)(((uint)((d >> 3) * 5243)) >> 17);
}

// Fused init: build bf16 layer-1 table WLt[col][k] (k<36: E@W1_l bucket k;
// 36..71: E@W1_r bucket k-36; 72: b1; 73..95: 0), bf16 stacked W2 table
// WstkT[col][k], zero bucket cursors, pack x into 1 word per node.
__global__ __launch_bounds__(256) void k_init(
    const int* __restrict__ x,
    const float* __restrict__ se, const float* __restrict__ ce,
    const float* __restrict__ pe,
    const float* __restrict__ W1l, const float* __restrict__ W1r,
    const float* __restrict__ b1,
    const float* __restrict__ W2l, const float* __restrict__ W2r,
    ushort* __restrict__ WLt, ushort* __restrict__ WstkT,
    int* __restrict__ gcur, int* __restrict__ xpk) {
    int t = blockIdx.x * 256 + threadIdx.x;
    if (t < 64 * 96) {
        int col = t / 96, k = t - (t / 96) * 96;
        float v = 0.f;
        if (k < 72) {
            int bkt = (k < 36) ? k : (k - 36);
            const float* erow; int f0;
            if (bkt < 8)       { erow = se + bkt * 16;        f0 = 0;  }
            else if (bkt < 16) { erow = ce + (bkt - 8) * 16;  f0 = 16; }
            else               { erow = pe + (bkt - 16) * 16; f0 = 32; }
            const float* W = (k < 36) ? W1l : W1r;
            float a = 0.f;
            #pragma unroll
            for (int f = 0; f < 16; ++f) a = fmaf(erow[f], W[(f0 + f) * 64 + col], a);
            v = a;
        } else if (k == 72) {
            v = b1[col];
        }
        WLt[t] = (ushort)f2bf(v);
    }
    if (t < 64 * 128) {
        int col = t >> 7, k = t & 127;
        float wv = (k < 64) ? W2r[k * 64 + col] : W2l[(k - 64) * 64 + col];
        WstkT[col * 128 + k] = (ushort)f2bf(wv);
    }
    if (t < NBUCK) gcur[t] = 0;
    for (int i = t; i < N_NODES; i += 256 * 256) {
        int xs = x[i * 3 + 0], xc = x[i * 3 + 1], xp = clampPos(x[i * 3 + 2]);
        xpk[i] = xs | (xc << 8) | (xp << 16);
    }
}

// Phase 1: bin edges by dst-bucket. LDS histogram + wave scan + LDS reorder,
// then bulk copy each bucket run to the fixed-stride binned buffer.
__global__ __launch_bounds__(256) void k_bin(const int* __restrict__ ei,
                                             int* __restrict__ gcur,
                                             int2* __restrict__ binned) {
    __shared__ int hist[NBUCK], offs[NBUCK], runc[NBUCK], gbase[NBUCK];
    __shared__ int2 stag[TILE];
    int tid = threadIdx.x;
    int tile_base = blockIdx.x * TILE;
    int tile_n = min(TILE, N_EDGES - tile_base);
    int n4 = tile_n >> 2;                       // N_EDGES%4==0 -> tile_n%4==0
    const int4* s4p = (const int4*)(ei + tile_base);
    const int4* d4p = (const int4*)(ei + N_EDGES + tile_base);

    for (int t = tid; t < NBUCK; t += 256) hist[t] = 0;
    __syncthreads();
    for (int k = tid; k < n4; k += 256) {
        int4 d4 = d4p[k];
        #pragma unroll
        for (int i = 0; i < 4; ++i) atomicAdd(&hist[bucketOf((&d4.x)[i])], 1);
    }
    __syncthreads();
    if (tid < 64) {                              // exclusive scan, wave 0
        int carry = 0;
        for (int c = 0; c < 8; ++c) {
            int idx = c * 64 + tid;
            int v = (idx < NBUCK) ? hist[idx] : 0;
            int orig = v;
            #pragma unroll
            for (int o = 1; o < 64; o <<= 1) {
                int u = __shfl_up(v, o);
                if (tid >= o) v += u;
            }
            if (idx < NBUCK) offs[idx] = carry + v - orig;
            carry += __shfl(v, 63);
        }
    }
    __syncthreads();
    for (int t = tid; t < NBUCK; t += 256) runc[t] = offs[t];
    __syncthreads();
    for (int k = tid; k < n4; k += 256) {        // reorder into LDS staging
        int4 d4 = d4p[k];
        int4 s4 = s4p[k];
        #pragma unroll
        for (int i = 0; i < 4; ++i) {
            int b = bucketOf((&d4.x)[i]);
            int pos = atomicAdd(&runc[b], 1);
            stag[pos] = make_int2((&s4.x)[i], (&d4.x)[i]);
        }
    }
    __syncthreads();
    for (int t = tid; t < NBUCK; t += 256) gbase[t] = atomAddI(&gcur[t], hist[t]);
    __syncthreads();
    for (int i = tid; i < tile_n; i += 256) {    // bulk copy runs to global
        int2 p = stag[i];
        int b = bucketOf(p.y);
        int o = gbase[b] + (i - offs[b]);
        if (o < BCAP) binned[(size_t)b * BCAP + o] = p;
    }
}

// Phase 2: one block per bucket; build 200 slab rows ENTIRELY in LDS (all
// slot atomics in LDS), then fully-coalesced copy-out.
__global__ __launch_bounds__(256) void k_place(const int2* __restrict__ binned,
                                               const int* __restrict__ gcur,
                                               int* __restrict__ cursor,
                                               int* __restrict__ slabA,
                                               int* __restrict__ slabB) {
    __shared__ int lslab[DPB][CAPA + CAPB];
    __shared__ int lcur[DPB];
    int b = blockIdx.x;
    int tid = threadIdx.x;
    if (tid < DPB) lcur[tid] = 0;
    __syncthreads();
    int n = min(gcur[b], BCAP);
    const int2* in = binned + (size_t)b * BCAP;
    for (int i = tid; i < n; i += 256) {
        int2 p = in[i];
        int local = p.y - b * DPB;
        int slot = atomicAdd(&lcur[local], 1);
        if (slot < CAPA + CAPB) lslab[local][slot] = p.x;
    }
    __syncthreads();
    for (int i = tid; i < DPB * CAPA; i += 256)
        slabA[b * DPB * CAPA + i] = lslab[i >> 4][i & 15];
    for (int i = tid; i < DPB * CAPB; i += 256)
        slabB[b * DPB * CAPB + i] = lslab[i >> 5][CAPA + (i & 31)];
    if (tid < DPB) cursor[b * DPB + tid] = lcur[tid];
}

__device__ __forceinline__ int slabAt(const int* __restrict__ slabA,
                                      const int* __restrict__ slabB,
                                      int row, int idx) {
    return (idx < CAPA) ? slabA[row * CAPA + idx] : slabB[row * CAPB + idx - CAPA];
}

// Layer 1 as MFMA: h1[16x64] = relu([cnt/deg | self-1hot | 1][16x96] @ WLt^T).
// Counts via LDS int atomics (3/neighbor); bf16 staging tile; 3 MFMAs/wave.
// Fragment labeling mirrors verified k_gemm: A row=lane&15, k=ks*32+(lane>>4)*8+e;
// C col=lane&15, row=(lane>>4)*4+reg.
__global__ __launch_bounds__(256) void k_layer1(
    const int* __restrict__ xpk, const int* __restrict__ cursor,
    const int* __restrict__ slabA, const int* __restrict__ slabB,
    const ushort* __restrict__ WLt, uint* __restrict__ AbU) {
    __shared__ int    cnt[16][104];     // stride 104: 16B-aligned, 2-way banks
    __shared__ ushort scnt[16][104];
    __shared__ float  sinv[16];
    __shared__ int    sdeg[16];
    int tid = threadIdx.x;
    int row0 = blockIdx.x * 16;
    for (int i = tid; i < 16 * 104; i += 256) cnt[i / 104][i % 104] = 0;
    if (tid < 16) {
        int dg = cursor[row0 + tid];
        sdeg[tid] = min(dg, CAPA + CAPB);
        sinv[tid] = 1.0f / fmaxf((float)dg, 1.0f);
    }
    __syncthreads();
    for (int i = tid; i < 16 * 48; i += 256) {   // neighbor bucket counting
        int r = i / 48, idx = i - r * 48;
        if (idx < sdeg[r]) {
            int p = xpk[slabAt(slabA, slabB, row0 + r, idx)];
            atomicAdd(&cnt[r][p & 0xff], 1);
            atomicAdd(&cnt[r][8 + ((p >> 8) & 0xff)], 1);
            atomicAdd(&cnt[r][16 + (p >> 16)], 1);
        }
    }
    if (tid < 16) {                              // self one-hot + bias (k=72)
        int p0 = xpk[row0 + tid];
        cnt[tid][36 + (p0 & 0xff)] = 1;
        cnt[tid][44 + ((p0 >> 8) & 0xff)] = 1;
        cnt[tid][52 + (p0 >> 16)] = 1;
        cnt[tid][72] = 1;
    }
    __syncthreads();
    for (int i = tid; i < 16 * 96; i += 256) {   // scale + cvt to bf16
        int r = i / 96, k = i - r * 96;
        float v = (float)cnt[r][k];
        if (k < 36) v *= sinv[r];
        scnt[r][k] = (ushort)f2bf(v);
    }
    __syncthreads();
    int w = tid >> 6, lane = tid & 63;
    int lo16 = lane & 15, hi4 = lane >> 4;
    f32x4 acc = {0.f, 0.f, 0.f, 0.f};
    #pragma unroll
    for (int ks = 0; ks < 3; ++ks) {
        short8 a8 = *(const short8*)(&scnt[lo16][ks * 32 + hi4 * 8]);
        short8 b8 = *(const short8*)(WLt + (w * 16 + lo16) * 96 + ks * 32 + hi4 * 8);
        acc = __builtin_amdgcn_mfma_f32_16x16x32_bf16(a8, b8, acc, 0, 0, 0);
    }
    #pragma unroll
    for (int r = 0; r < 4; ++r) {                // relu -> packed bf16 pairs
        uint rb = f2bf(fmaxf(acc[r], 0.0f));
        uint nxt = __shfl_down(rb, 1);
        if ((lo16 & 1) == 0) {
            int node = row0 + hi4 * 4 + r;
            AbU[(size_t)node * 64 + ((w * 16 + lo16) >> 1)] = rb | (nxt << 16);
        }
    }
}

// Layer-2 neighbor mean from bf16 self-half of Ab; writes bf16 agg-half.
__global__ __launch_bounds__(256) void k_gather(
    uint* __restrict__ AbU, const int* __restrict__ cursor,
    const int* __restrict__ slabA, const int* __restrict__ slabB) {
    int gid = blockIdx.x * 256 + threadIdx.x;
    int wid = gid >> 6;
    int lane = threadIdx.x & 63;
    int half = lane >> 5, l = lane & 31;
    int row = wid * 2 + half;
    if (row >= N_NODES) return;
    int deg = cursor[row];
    int m = min(deg, CAPA + CAPB);
    int nb0 = (l < m)      ? slabAt(slabA, slabB, row, l)      : 0;
    int nb1 = (l + 32 < m) ? slabB[row * CAPB + l + 32 - CAPA] : 0;
    float ax = 0.f, ay = 0.f;
    int d = 0;
    for (; d + 2 <= m; d += 2) {
        int s0 = __shfl((d < 32) ? nb0 : nb1, (half << 5) | (d & 31));
        int s1 = __shfl((d + 1 < 32) ? nb0 : nb1, (half << 5) | ((d + 1) & 31));
        uint v0 = AbU[(size_t)s0 * 64 + l];
        uint v1 = AbU[(size_t)s1 * 64 + l];
        ax += __uint_as_float(v0 << 16) + __uint_as_float(v1 << 16);
        ay += __uint_as_float(v0 & 0xffff0000u) + __uint_as_float(v1 & 0xffff0000u);
    }
    if (d < m) {
        int s = __shfl((d < 32) ? nb0 : nb1, (half << 5) | (d & 31));
        uint v = AbU[(size_t)s * 64 + l];
        ax += __uint_as_float(v << 16);
        ay += __uint_as_float(v & 0xffff0000u);
    }
    float inv = 1.0f / fmaxf((float)deg, 1.0f);
    AbU[(size_t)row * 64 + 32 + l] = f2bf(ax * inv) | (f2bf(ay * inv) << 16);
}

// h2 = relu( [h1|agg](bf16, K=128) @ [W2r;W2l] + b2 ) via MFMA 16x16x32 bf16.
__global__ __launch_bounds__(256) void k_gemm(
    const uint* __restrict__ AbU, const ushort* __restrict__ WstkT,
    const float* __restrict__ b2, float* __restrict__ h2) {
    int w = threadIdx.x >> 6, lane = threadIdx.x & 63;
    int lo16 = lane & 15, hi4 = lane >> 4;
    short8 bfr[4][4];
    #pragma unroll
    for (int nb = 0; nb < 4; ++nb) {
        #pragma unroll
        for (int kb = 0; kb < 4; ++kb)
            bfr[nb][kb] = *(const short8*)(WstkT + (nb * 16 + lo16) * 128 + kb * 32 + hi4 * 8);
    }
    float bb[4];
    #pragma unroll
    for (int nb = 0; nb < 4; ++nb) bb[nb] = b2[nb * 16 + lo16];

    int row0 = blockIdx.x * 64 + w * 16;
    int arow = min(row0 + lo16, N_NODES - 1);
    const short8* Arow = (const short8*)(AbU + (size_t)arow * 64);
    short8 a8[4];
    #pragma unroll
    for (int kb = 0; kb < 4; ++kb) a8[kb] = Arow[kb * 4 + hi4];   // k = kb*32+hi4*8+e

    f32x4 acc[4] = {{0,0,0,0},{0,0,0,0},{0,0,0,0},{0,0,0,0}};
    #pragma unroll
    for (int kb = 0; kb < 4; ++kb) {
        #pragma unroll
        for (int nb = 0; nb < 4; ++nb)
            acc[nb] = __builtin_amdgcn_mfma_f32_16x16x32_bf16(a8[kb], bfr[nb][kb], acc[nb], 0, 0, 0);
    }
    #pragma unroll
    for (int nb = 0; nb < 4; ++nb) {
        #pragma unroll
        for (int r = 0; r < 4; ++r) {
            int orow = row0 + hi4 * 4 + r;
            if (orow < N_NODES)
                h2[(size_t)orow * 64 + nb * 16 + lo16] = fmaxf(acc[nb][r] + bb[nb], 0.f);
        }
    }
}

__device__ __forceinline__ int lowerBound(const int* __restrict__ b, int n, int v) {
    int lo = 0, hi = n;
    while (lo < hi) { int mid = (lo + hi) >> 1; if (b[mid] < v) lo = mid + 1; else hi = mid; }
    return lo;
}

// Fused graph mean-pool + classifier; 4 independent partial sums.
__global__ __launch_bounds__(256) void k_pool_final(
    const float* __restrict__ h2, const int* __restrict__ batch,
    const float* __restrict__ Wc, const float* __restrict__ bc,
    float* __restrict__ out) {
    int g = blockIdx.x * 4 + (threadIdx.x >> 6);
    if (g >= N_GRAPHS) return;
    int j = threadIdx.x & 63;
    int lo = lowerBound(batch, N_NODES, g);
    int hi = lowerBound(batch, N_NODES, g + 1);
    float a0 = 0.f, a1 = 0.f, a2 = 0.f, a3 = 0.f;
    int n = lo;
    for (; n + 4 <= hi; n += 4) {
        a0 += h2[(size_t)n * 64 + j];
        a1 += h2[(size_t)(n + 1) * 64 + j];
        a2 += h2[(size_t)(n + 2) * 64 + j];
        a3 += h2[(size_t)(n + 3) * 64 + j];
    }
    for (; n < hi; ++n) a0 += h2[(size_t)n * 64 + j];
    float mean = ((a0 + a1) + (a2 + a3)) / fmaxf((float)(hi - lo), 1.0f);
    #pragma unroll
    for (int c = 0; c < 10; ++c) {
        float p = mean * Wc[j * 10 + c];
        #pragma unroll
        for (int off = 32; off >= 1; off >>= 1) p += __shfl_down(p, off);
        if (j == 0) out[g * 10 + c] = p + bc[c];
    }
}

extern "C" void kernel_launch(void* const* d_in, const int* in_sizes, int n_in,
                              void* d_out, int out_size, void* d_ws, size_t ws_size,
                              hipStream_t stream) {
    const int* x     = (const int*)d_in[0];
    const int* ei    = (const int*)d_in[1];
    const int* batch = (const int*)d_in[2];
    const float* se  = (const float*)d_in[4];
    const float* ce  = (const float*)d_in[5];
    const float* pe  = (const float*)d_in[6];
    const float* W1l = (const float*)d_in[7];
    const float* W1r = (const float*)d_in[8];
    const float* b1  = (const float*)d_in[9];
    const float* W2l = (const float*)d_in[10];
    const float* W2r = (const float*)d_in[11];
    const float* b2  = (const float*)d_in[12];
    const float* Wc  = (const float*)d_in[13];
    const float* bc  = (const float*)d_in[14];

    float* ws    = (float*)d_ws;
    uint*  AbU   = (uint*)ws;                   // [0, 6.4M) packed bf16 [N][64]
    float* h2    = ws + 6400000;                // [6.4M, 12.8M)
    int2*  binned= (int2*)ws;                   // aliases AbU+h2 (dead before both)
    int*   slabA = (int*)(ws + 12800000);       // 1.6M ints (100k x 16)
    int*   slabB = (int*)(ws + 14400000);       // 3.2M ints (100k x 32)
    int*   cursor= (int*)(ws + 17600000);       // 100k
    int*   xpk   = (int*)(ws + 17700000);       // 100k
    ushort* WstkT= (ushort*)(ws + 17806000);    // 8192 ushorts
    ushort* WLt  = (ushort*)(ws + 17810100);    // 6144 ushorts (16B-aligned)
    int*   gcur  = (int*)(ws + 17814000);       // 500 bucket cursors

    k_init<<<256, 256, 0, stream>>>(x, se, ce, pe, W1l, W1r, b1, W2l, W2r,
                                    WLt, WstkT, gcur, xpk);
    k_bin<<<(N_EDGES + TILE - 1) / TILE, 256, 0, stream>>>(ei, gcur, binned);
    k_place<<<NBUCK, 256, 0, stream>>>(binned, gcur, cursor, slabA, slabB);
    k_layer1<<<N_NODES / 16, 256, 0, stream>>>(xpk, cursor, slabA, slabB, WLt, AbU);
    k_gather<<<12500, 256, 0, stream>>>(AbU, cursor, slabA, slabB);
    k_gemm<<<(N_NODES + 63) / 64, 256, 0, stream>>>(AbU, WstkT, b2, h2);
    k_pool_final<<<(N_GRAPHS + 3) / 4, 256, 0, stream>>>(h2, batch, Wc, bc, (float*)d_out);
}